// Round 13
// baseline (403.647 us; speedup 1.0000x reference)
//
#include <hip/hip_runtime.h>

// LQR KKT solve via backward Riccati recursion + forward rollout.
// T=128, n_state=16, n_ctrl=8, n_all=24. Single block, 256 threads.
// Base: proven R9 (320us). Deltas (scheduling only + one proven merge):
//  (1) DEFERRED EXPORTS: step-t Pws/Fws/pws/dws stores issue at the start
//      of the NEXT step's phase 1 (values carried in registers), so the
//      per-barrier vmcnt drain hipcc emits has ~500cy-old stores to wait
//      on (≈0 exposed) instead of just-issued ones.
//  (2) C-prefetch issued at top of phase 2 (consumed phase 4): its L2
//      latency hides under phase-2 content instead of being exposed at
//      the phase-1 barrier drain.
//  (3) merged GJ round 2 into the update phase (4 phases/step): algebra
//      byte-identical to R10 which PASSED; R10's slowdown was its asm
//      barriers (R11 isolated). Builtin __syncthreads() ONLY here.
// Banned by experiment: Gu dual-write (R3-R5), asm light barriers (R11),
// sched_barrier (R10), 1-wave layout (R8), per-lane 8x8 LU (R12).
// mu_t = P_t x_t + p_t (stable). Forward pass identical to R9.
// d_ws: Pws[T*256] | pws[T*16] | Fws[T*256] | dws[T*16].

constexpr int T  = 128;
constexpr int NA = 24;

// 16-elem dot: LDS float4 stream x register-resident row.
__device__ __forceinline__ float dot16r(const float* lds, const float* r, float s) {
    const float4* a4 = (const float4*)lds;
#pragma unroll
    for (int q = 0; q < 4; ++q) {
        float4 x = a4[q];
        s = fmaf(x.x, r[4 * q + 0], s); s = fmaf(x.y, r[4 * q + 1], s);
        s = fmaf(x.z, r[4 * q + 2], s); s = fmaf(x.w, r[4 * q + 3], s);
    }
    return s;
}
// 16-elem dot: both operands LDS float4.
__device__ __forceinline__ float dot16f4(const float* a, const float* b, float s) {
    const float4* a4 = (const float4*)a;
    const float4* b4 = (const float4*)b;
#pragma unroll
    for (int q = 0; q < 4; ++q) {
        float4 x = a4[q], y = b4[q];
        s = fmaf(x.x, y.x, s); s = fmaf(x.y, y.y, s);
        s = fmaf(x.z, y.z, s); s = fmaf(x.w, y.w, s);
    }
    return s;
}

__global__ __launch_bounds__(256, 1)
void lqr_solve(const float* __restrict__ gA,
               const float* __restrict__ gB,
               const float* __restrict__ gx0,
               const float* __restrict__ gC,
               const float* __restrict__ gc,
               float* __restrict__ out,
               float* __restrict__ Pws,   // [T*256] P_t row-major
               float* __restrict__ pws,   // [T*16]  p_t
               float* __restrict__ Fws,   // [T*256] F_t = A - B K_t
               float* __restrict__ dws)   // [T*16]  d_t = -B k_t
{
    __shared__ __align__(16) float A_sh[16][16];
    __shared__ __align__(16) float At_sh[16][16];
    __shared__ __align__(16) float B_sh[16][8];
    __shared__ __align__(16) float Bt_sh[8][16];
    __shared__ __align__(16) float P_sh[2][16][20];
    __shared__ __align__(16) float p_sh[2][16];
    __shared__ __align__(16) float Wt[16][20];
    __shared__ __align__(16) float Vt[8][20];
    __shared__ __align__(16) float Gu[16][8];
    __shared__ __align__(16) float Aug[2][8][28];  // stride 28: [y][4] aligned
    __shared__ __align__(16) float Kall[T][8][16];
    __shared__ __align__(16) float kall[T][8];
    __shared__ __align__(16) float c_sh[T][NA];
    __shared__ __align__(16) float z_sh[T][NA];
    __shared__ __align__(16) float Csh[2][24][25];

    const int tid = threadIdx.x;

    // ---- init staging (identical to R9) ----
    {
        const int i = tid >> 4, j = tid & 15;
        const float v = gA[tid];
        A_sh[i][j] = v; At_sh[j][i] = v;
        P_sh[0][i][j] = 0.0f;
        if (j < 4) P_sh[0][i][16 + j] = 0.0f;
    }
    if (tid < 128) {
        const int i = tid >> 3, j = tid & 7;
        const float v = gB[tid];
        B_sh[i][j] = v; Bt_sh[j][i] = v;
    }
    if (tid < 16) p_sh[0][tid] = 0.0f;
    for (int idx = tid; idx < T * NA; idx += 256) c_sh[idx / NA][idx % NA] = gc[idx];
    for (int idx = tid; idx < 576; idx += 256)
        Csh[0][idx / 24][idx % 24] = gC[(T - 1) * 576 + idx];
    __syncthreads();

    // ---- per-lane register caches of invariant rows ----
    float atr[16], btr_e[16], btr3[16], atr2[16], brow[8], browp[8];
    {
        const int rA  = tid >> 4;
        const int rBe = (tid >> 4) & 7;
        const int rB3 = (tid / 25) & 7;
        const int rA2 = (tid >> 3) & 15;
        const int rBp = tid & 15;
#pragma unroll
        for (int q = 0; q < 4; ++q) {
            float4 v;
            v = *(const float4*)&At_sh[rA][4 * q];
            atr[4*q]=v.x; atr[4*q+1]=v.y; atr[4*q+2]=v.z; atr[4*q+3]=v.w;
            v = *(const float4*)&Bt_sh[rBe][4 * q];
            btr_e[4*q]=v.x; btr_e[4*q+1]=v.y; btr_e[4*q+2]=v.z; btr_e[4*q+3]=v.w;
            v = *(const float4*)&Bt_sh[rB3][4 * q];
            btr3[4*q]=v.x; btr3[4*q+1]=v.y; btr3[4*q+2]=v.z; btr3[4*q+3]=v.w;
            v = *(const float4*)&At_sh[rA2][4 * q];
            atr2[4*q]=v.x; atr2[4*q+1]=v.y; atr2[4*q+2]=v.z; atr2[4*q+3]=v.w;
        }
#pragma unroll
        for (int q = 0; q < 2; ++q) {
            float4 v;
            v = *(const float4*)&B_sh[rA][4 * q];
            brow[4*q]=v.x; brow[4*q+1]=v.y; brow[4*q+2]=v.z; brow[4*q+3]=v.w;
            v = *(const float4*)&B_sh[rBp][4 * q];
            browp[4*q]=v.x; browp[4*q+1]=v.y; browp[4*q+2]=v.z; browp[4*q+3]=v.w;
        }
    }

    // deferred-export registers (step t+1 values, stored in step t phase 1)
    float sv_p = 0.f, sv_f = 0.f, sv_vp = 0.f, sv_da = 0.f;

    // ---- backward Riccati: 4 phases per step ----
    int pb = 0;
    for (int t = T - 1; t >= 0; --t) {
        const int cb = (T - 1 - t) & 1;

        // phase 1: deferred exports for step t+1, then W/V compute
        if (t != T - 1) {
            Pws[(t + 1) * 256 + tid] = sv_p;
            Fws[(t + 1) * 256 + tid] = sv_f;
            if (tid < 16) {
                pws[(t + 1) * 16 + tid] = sv_vp;
                dws[(t + 1) * 16 + tid] = sv_da;
            }
        }
        {
            const int j = tid >> 4, k = tid & 15;
            Wt[j][k] = dot16r(&P_sh[pb][k][0], atr, 0.0f);
            if (tid < 128) {
                Vt[j][k] = dot16r(&P_sh[pb][k][0], btr_e, 0.0f);
            }
        }
        __syncthreads();

        // phase 2: C-prefetch issue (consumed phase 4) + Aug[0] + Gu
        float pf0 = 0.f, pf1 = 0.f, pf2 = 0.f;
        if (t > 0) {
            const float* src = gC + (size_t)(t - 1) * 576;
            pf0 = src[tid];
            pf1 = src[tid + 256];
            if (tid < 64) pf2 = src[tid + 512];
        }
        if (tid < 200) {
            const int i = tid / 25, j = tid % 25;
            float s;
            if (j < 8) {
                s = dot16r(&Vt[j][0], btr3, Csh[cb][16 + i][16 + j]);
            } else if (j < 24) {
                const int jj = j - 8;
                s = dot16r(&Wt[jj][0], btr3, Csh[cb][16 + i][jj]);
            } else {
                s = dot16r(&p_sh[pb][0], btr3, c_sh[t][16 + i]);
            }
            Aug[0][i][j] = s;
        }
        if (tid < 128) {
            const int i = tid >> 3, j = tid & 7;
            Gu[i][j] = dot16r(&Vt[j][0], atr2, Csh[cb][i][16 + j]);
        }
        __syncthreads();

        // phase 3: GJ round 1 (4x4 block pivot rows/cols 0..3): Aug[0]->Aug[1]
        {
            const float4 r0 = *(const float4*)&Aug[0][0][0];
            const float4 r1 = *(const float4*)&Aug[0][1][0];
            const float4 r2 = *(const float4*)&Aug[0][2][0];
            const float4 r3 = *(const float4*)&Aug[0][3][0];
            const float m00=r0.x, m01=r0.y, m02=r0.z, m03=r0.w;
            const float m10=r1.x, m11=r1.y, m12=r1.z, m13=r1.w;
            const float m20=r2.x, m21=r2.y, m22=r2.z, m23=r2.w;
            const float m30=r3.x, m31=r3.y, m32=r3.z, m33=r3.w;
            const float ra   = 1.0f / fmaf(m00, m11, -m01 * m10);
            const float ai00 =  m11 * ra, ai01 = -m01 * ra;
            const float ai10 = -m10 * ra, ai11 =  m00 * ra;
            const float aib00 = ai00*m02 + ai01*m12, aib01 = ai00*m03 + ai01*m13;
            const float aib10 = ai10*m02 + ai11*m12, aib11 = ai10*m03 + ai11*m13;
            const float s00 = m22 - (m20*aib00 + m21*aib10);
            const float s01 = m23 - (m20*aib01 + m21*aib11);
            const float s10 = m32 - (m30*aib00 + m31*aib10);
            const float s11 = m33 - (m30*aib01 + m31*aib11);
            const float rs   = 1.0f / fmaf(s00, s11, -s01 * s10);
            const float si00 =  s11 * rs, si01 = -s01 * rs;
            const float si10 = -s10 * rs, si11 =  s00 * rs;
            if (tid < 200) {
                const int i = tid / 25, j = tid % 25;
                const float pt0 = Aug[0][0][j], pt1 = Aug[0][1][j];
                const float pq0 = Aug[0][2][j], pq1 = Aug[0][3][j];
                const float y0 = ai00*pt0 + ai01*pt1;
                const float y1 = ai10*pt0 + ai11*pt1;
                const float z0 = pq0 - (m20*y0 + m21*y1);
                const float z1 = pq1 - (m30*y0 + m31*y1);
                const float w2 = si00*z0 + si01*z1;
                const float w3 = si10*z0 + si11*z1;
                const float w0 = y0 - (aib00*w2 + aib01*w3);
                const float w1 = y1 - (aib10*w2 + aib11*w3);
                float v;
                if      (i == 0) v = w0;
                else if (i == 1) v = w1;
                else if (i == 2) v = w2;
                else if (i == 3) v = w3;
                else {
                    const float4 e = *(const float4*)&Aug[0][i][0];
                    v = Aug[0][i][j]
                        - (e.x*w0 + e.y*w1 + e.z*w2 + e.w*w3);
                }
                Aug[1][i][j] = v;
            }
        }
        __syncthreads();

        // phase 4 (merged GJ round 2 + updates; algebra == R10 which PASSED)
        if (t > 0) {  // commit prefetched C_{t-1} (regs -> other Csh buffer)
            Csh[cb ^ 1][tid / 24][tid % 24] = pf0;
            Csh[cb ^ 1][(tid + 256) / 24][(tid + 256) % 24] = pf1;
            if (tid < 64) Csh[cb ^ 1][(tid + 512) / 24][(tid + 512) % 24] = pf2;
        }
        {
            // round-2 pivot block M = Aug[1][4:8][4:8] (16B-aligned reads)
            const float4 q4 = *(const float4*)&Aug[1][4][4];
            const float4 q5 = *(const float4*)&Aug[1][5][4];
            const float4 q6 = *(const float4*)&Aug[1][6][4];
            const float4 q7 = *(const float4*)&Aug[1][7][4];
            const float m00=q4.x, m01=q4.y, m02=q4.z, m03=q4.w;
            const float m10=q5.x, m11=q5.y, m12=q5.z, m13=q5.w;
            const float m20=q6.x, m21=q6.y, m22=q6.z, m23=q6.w;
            const float m30=q7.x, m31=q7.y, m32=q7.z, m33=q7.w;
            const float ra   = 1.0f / fmaf(m00, m11, -m01 * m10);
            const float ai00 =  m11 * ra, ai01 = -m01 * ra;
            const float ai10 = -m10 * ra, ai11 =  m00 * ra;
            const float aib00 = ai00*m02 + ai01*m12, aib01 = ai00*m03 + ai01*m13;
            const float aib10 = ai10*m02 + ai11*m12, aib11 = ai10*m03 + ai11*m13;
            const float s00 = m22 - (m20*aib00 + m21*aib10);
            const float s01 = m23 - (m20*aib01 + m21*aib11);
            const float s10 = m32 - (m30*aib00 + m31*aib10);
            const float s11 = m33 - (m30*aib01 + m31*aib11);
            const float rs   = 1.0f / fmaf(s00, s11, -s01 * s10);
            const float si00 =  s11 * rs, si01 = -s01 * rs;
            const float si10 = -s10 * rs, si11 =  s00 * rs;
            const float4 e0 = *(const float4*)&Aug[1][0][4];
            const float4 e1 = *(const float4*)&Aug[1][1][4];
            const float4 e2 = *(const float4*)&Aug[1][2][4];
            const float4 e3 = *(const float4*)&Aug[1][3][4];

            const int i = tid >> 4, j = tid & 15;
            const int cj = 8 + j;
            float kc[8];
            {
                const float pt0 = Aug[1][4][cj], pt1 = Aug[1][5][cj];
                const float pq0 = Aug[1][6][cj], pq1 = Aug[1][7][cj];
                const float y0 = ai00*pt0 + ai01*pt1;
                const float y1 = ai10*pt0 + ai11*pt1;
                const float z0 = pq0 - (m20*y0 + m21*y1);
                const float z1 = pq1 - (m30*y0 + m31*y1);
                const float w2 = si00*z0 + si01*z1;
                const float w3 = si10*z0 + si11*z1;
                const float w0 = y0 - (aib00*w2 + aib01*w3);
                const float w1 = y1 - (aib10*w2 + aib11*w3);
                kc[4]=w0; kc[5]=w1; kc[6]=w2; kc[7]=w3;
                kc[0] = Aug[1][0][cj] - (e0.x*w0 + e0.y*w1 + e0.z*w2 + e0.w*w3);
                kc[1] = Aug[1][1][cj] - (e1.x*w0 + e1.y*w1 + e1.z*w2 + e1.w*w3);
                kc[2] = Aug[1][2][cj] - (e2.x*w0 + e2.y*w1 + e2.z*w2 + e2.w*w3);
                kc[3] = Aug[1][3][cj] - (e3.x*w0 + e3.y*w1 + e3.z*w2 + e3.w*w3);
            }
            if (i < 8) {  // export K (select-chain, static indices)
                float kv = kc[0];
                if (i == 1) kv = kc[1]; else if (i == 2) kv = kc[2];
                else if (i == 3) kv = kc[3]; else if (i == 4) kv = kc[4];
                else if (i == 5) kv = kc[5]; else if (i == 6) kv = kc[6];
                else if (i == 7) kv = kc[7];
                Kall[t][i][j] = kv;
            }
            // P-update -> LDS + deferred reg; F -> deferred reg
            float s = dot16r(&Wt[j][0], atr, Csh[cb][i][j]);
            float s2 = 0.f, fa = 0.f;
            const float4 g0 = *(const float4*)&Gu[i][0];
            const float4 g1 = *(const float4*)&Gu[i][4];
            s2 = fmaf(g0.x, kc[0], s2); s2 = fmaf(g0.y, kc[1], s2);
            s2 = fmaf(g0.z, kc[2], s2); s2 = fmaf(g0.w, kc[3], s2);
            s2 = fmaf(g1.x, kc[4], s2); s2 = fmaf(g1.y, kc[5], s2);
            s2 = fmaf(g1.z, kc[6], s2); s2 = fmaf(g1.w, kc[7], s2);
#pragma unroll
            for (int y = 0; y < 8; ++y) fa = fmaf(brow[y], kc[y], fa);
            const float v = s - s2;
            P_sh[pb ^ 1][i][j] = v;
            sv_p = v;
            sv_f = A_sh[i][j] - fa;
            // p/d updates (lanes < 16): solve col 24
            if (tid < 16) {
                float kk8[8];
                const float pt0 = Aug[1][4][24], pt1 = Aug[1][5][24];
                const float pq0 = Aug[1][6][24], pq1 = Aug[1][7][24];
                const float y0 = ai00*pt0 + ai01*pt1;
                const float y1 = ai10*pt0 + ai11*pt1;
                const float z0 = pq0 - (m20*y0 + m21*y1);
                const float z1 = pq1 - (m30*y0 + m31*y1);
                const float w2 = si00*z0 + si01*z1;
                const float w3 = si10*z0 + si11*z1;
                const float w0 = y0 - (aib00*w2 + aib01*w3);
                const float w1 = y1 - (aib10*w2 + aib11*w3);
                kk8[4]=w0; kk8[5]=w1; kk8[6]=w2; kk8[7]=w3;
                kk8[0] = Aug[1][0][24] - (e0.x*w0 + e0.y*w1 + e0.z*w2 + e0.w*w3);
                kk8[1] = Aug[1][1][24] - (e1.x*w0 + e1.y*w1 + e1.z*w2 + e1.w*w3);
                kk8[2] = Aug[1][2][24] - (e2.x*w0 + e2.y*w1 + e2.z*w2 + e2.w*w3);
                kk8[3] = Aug[1][3][24] - (e3.x*w0 + e3.y*w1 + e3.z*w2 + e3.w*w3);
                if (tid < 8) {
                    float kv = kk8[0];
                    if (tid == 1) kv = kk8[1]; else if (tid == 2) kv = kk8[2];
                    else if (tid == 3) kv = kk8[3]; else if (tid == 4) kv = kk8[4];
                    else if (tid == 5) kv = kk8[5]; else if (tid == 6) kv = kk8[6];
                    else if (tid == 7) kv = kk8[7];
                    kall[t][tid] = kv;
                }
                float sp = dot16f4(&At_sh[tid][0], &p_sh[pb][0], c_sh[t][tid]);
                float sp2 = 0.f, da = 0.f;
#pragma unroll
                for (int q = 0; q < 8; ++q) {
                    sp2 = fmaf(Gu[tid][q], kk8[q], sp2);
                    da  = fmaf(browp[q],  kk8[q], da);
                }
                const float vp = sp - sp2;
                p_sh[pb ^ 1][tid] = vp;
                sv_vp = vp;
                sv_da = -da;
            }
        }
        __syncthreads();
        pb ^= 1;
    }

    // store the final (t=0) deferred exports, then full drain
    Pws[tid] = sv_p;
    Fws[tid] = sv_f;
    if (tid < 16) { pws[tid] = sv_vp; dws[tid] = sv_da; }
    __syncthreads();
    asm volatile("s_waitcnt vmcnt(0)" ::: "memory");

    // ---- forward rollout: one phase per step (identical to R9) ----
    if (tid < 16) z_sh[0][tid] = gx0[tid];
    float fcur[16], dcur = 0.f, prow[16], pcur = 0.f;
    if (tid < 16) {
#pragma unroll
        for (int q = 0; q < 4; ++q) {
            float4 v = *(const float4*)&Fws[tid * 16 + 4 * q];
            fcur[4*q]=v.x; fcur[4*q+1]=v.y; fcur[4*q+2]=v.z; fcur[4*q+3]=v.w;
        }
        dcur = dws[tid];
    }
    if (tid >= 32 && tid < 48) {
        const int i = tid - 32;
#pragma unroll
        for (int q = 0; q < 4; ++q) {
            float4 v = *(const float4*)&Pws[i * 16 + 4 * q];
            prow[4*q]=v.x; prow[4*q+1]=v.y; prow[4*q+2]=v.z; prow[4*q+3]=v.w;
        }
        pcur = pws[i];
    }
    __syncthreads();
    for (int t = 0; t < T; ++t) {
        float fn[16], dn = 0.f, pn[16], ppn = 0.f;
        if (t < T - 1) {
            if (tid < 16) {
#pragma unroll
                for (int q = 0; q < 4; ++q) {
                    float4 v = *(const float4*)&Fws[(t + 1) * 256 + tid * 16 + 4 * q];
                    fn[4*q]=v.x; fn[4*q+1]=v.y; fn[4*q+2]=v.z; fn[4*q+3]=v.w;
                }
                dn = dws[(t + 1) * 16 + tid];
            }
            if (tid >= 32 && tid < 48) {
                const int i = tid - 32;
#pragma unroll
                for (int q = 0; q < 4; ++q) {
                    float4 v = *(const float4*)&Pws[(t + 1) * 256 + i * 16 + 4 * q];
                    pn[4*q]=v.x; pn[4*q+1]=v.y; pn[4*q+2]=v.z; pn[4*q+3]=v.w;
                }
                ppn = pws[(t + 1) * 16 + i];
            }
        }
        if (tid >= 16 && tid < 24) {        // u_t = -(K_t x_t + k_t)
            const int y = tid - 16;
            float s = dot16f4(&Kall[t][y][0], &z_sh[t][0], kall[t][y]);
            z_sh[t][16 + y] = -s;
        }
        if (tid >= 32 && tid < 48) {        // mu_t = +/- (P_t x_t + p_t)
            const int i = tid - 32;
            float s = pcur;
            const float4* zr = (const float4*)&z_sh[t][0];
#pragma unroll
            for (int q = 0; q < 4; ++q) {
                float4 z = zr[q];
                s = fmaf(prow[4*q+0], z.x, s); s = fmaf(prow[4*q+1], z.y, s);
                s = fmaf(prow[4*q+2], z.z, s); s = fmaf(prow[4*q+3], z.w, s);
            }
            if (t == 0) s = -s;
            out[T * NA + t * 16 + i] = s;
        }
        if (t < T - 1 && tid < 16) {        // x_{t+1} = F_t x_t + d_t
            const float4* zr = (const float4*)&z_sh[t][0];
            float s = dcur;
#pragma unroll
            for (int q = 0; q < 4; ++q) {
                float4 z = zr[q];
                s = fmaf(fcur[4*q+0], z.x, s); s = fmaf(fcur[4*q+1], z.y, s);
                s = fmaf(fcur[4*q+2], z.z, s); s = fmaf(fcur[4*q+3], z.w, s);
            }
            z_sh[t + 1][tid] = s;
        }
        __syncthreads();
        if (t < T - 1) {
            if (tid < 16) {
#pragma unroll
                for (int q = 0; q < 16; ++q) fcur[q] = fn[q];
                dcur = dn;
            }
            if (tid >= 32 && tid < 48) {
#pragma unroll
                for (int q = 0; q < 16; ++q) prow[q] = pn[q];
                pcur = ppn;
            }
        }
    }

    // ---- write z ----
    for (int idx = tid; idx < T * NA; idx += 256)
        out[idx] = z_sh[idx / 24][idx % 24];
}

extern "C" void kernel_launch(void* const* d_in, const int* in_sizes, int n_in,
                              void* d_out, int out_size, void* d_ws, size_t ws_size,
                              hipStream_t stream) {
    const float* gA  = (const float*)d_in[0];
    const float* gB  = (const float*)d_in[1];
    const float* gx0 = (const float*)d_in[2];
    const float* gC  = (const float*)d_in[3];
    const float* gc  = (const float*)d_in[4];
    float* out = (float*)d_out;
    float* Pws = (float*)d_ws;           // T*256 floats
    float* pws = Pws + T * 256;          // T*16
    float* Fws = pws + T * 16;           // T*256
    float* dws = Fws + T * 256;          // T*16
    lqr_solve<<<dim3(1), dim3(256), 0, stream>>>(gA, gB, gx0, gC, gc, out,
                                                 Pws, pws, Fws, dws);
}

// Round 14
// 364.519 us; speedup vs baseline: 1.1073x; 1.1073x over previous
//
#include <hip/hip_runtime.h>

// LQR KKT solve via backward Riccati recursion + forward rollout.
// T=128, n_state=16, n_ctrl=8, n_all=24. Single block, 256 threads.
// Base: proven R9 (320us, absmax 0.002) -- backward pass byte-identical.
// SINGLE delta: forward rollout rewritten barrier-free.
//   (a) x-chain in registers: lanes 0..15 of wave 0 hold x_t[l]; per step
//       x_{t+1}[l] = d_t[l] + sum_q F_t[l][q] * __shfl(x, q, 16).
//       16 shfl + 16 FMA per step, no barrier, no LDS in the chain.
//       F_t/d_t streamed from L2 with one-step register prefetch.
//       x_t written to xs[t][l] (LDS) for the epilogue.
//   (b) ONE parallel epilogue phase computes all u_t = -(K x + k),
//       mu_t = +/-(P x + p), and the z copy (128 forward barriers -> 1).
// Ban list (all measured): Gu dual-write (R3-R5), 1-wave compute (R8),
// asm light barriers (R11), sched_barrier (R10), per-lane 8x8 LU (R12),
// merged GJ round 2 (R10/R13, ~+40us). Builtin __syncthreads() only.
// d_ws: Pws[T*256] | pws[T*16] | Fws[T*256] | dws[T*16].

constexpr int T  = 128;
constexpr int NA = 24;

// 16-elem dot: LDS float4 stream x register-resident row.
__device__ __forceinline__ float dot16r(const float* lds, const float* r, float s) {
    const float4* a4 = (const float4*)lds;
#pragma unroll
    for (int q = 0; q < 4; ++q) {
        float4 x = a4[q];
        s = fmaf(x.x, r[4 * q + 0], s); s = fmaf(x.y, r[4 * q + 1], s);
        s = fmaf(x.z, r[4 * q + 2], s); s = fmaf(x.w, r[4 * q + 3], s);
    }
    return s;
}
// 16-elem dot: both operands LDS float4.
__device__ __forceinline__ float dot16f4(const float* a, const float* b, float s) {
    const float4* a4 = (const float4*)a;
    const float4* b4 = (const float4*)b;
#pragma unroll
    for (int q = 0; q < 4; ++q) {
        float4 x = a4[q], y = b4[q];
        s = fmaf(x.x, y.x, s); s = fmaf(x.y, y.y, s);
        s = fmaf(x.z, y.z, s); s = fmaf(x.w, y.w, s);
    }
    return s;
}

__global__ __launch_bounds__(256, 1)
void lqr_solve(const float* __restrict__ gA,
               const float* __restrict__ gB,
               const float* __restrict__ gx0,
               const float* __restrict__ gC,
               const float* __restrict__ gc,
               float* __restrict__ out,
               float* __restrict__ Pws,   // [T*256] P_t row-major
               float* __restrict__ pws,   // [T*16]  p_t
               float* __restrict__ Fws,   // [T*256] F_t = A - B K_t
               float* __restrict__ dws)   // [T*16]  d_t = -B k_t
{
    __shared__ __align__(16) float A_sh[16][16];
    __shared__ __align__(16) float At_sh[16][16];
    __shared__ __align__(16) float B_sh[16][8];
    __shared__ __align__(16) float Bt_sh[8][16];
    __shared__ __align__(16) float P_sh[2][16][20];
    __shared__ __align__(16) float p_sh[2][16];
    __shared__ __align__(16) float Wt[16][20];
    __shared__ __align__(16) float Vt[8][20];
    __shared__ __align__(16) float Gu[16][8];
    __shared__ __align__(16) float Aug[2][8][28];
    __shared__ __align__(16) float Kall[T][8][16];
    __shared__ __align__(16) float kall[T][8];
    __shared__ __align__(16) float c_sh[T][NA];
    __shared__ __align__(16) float xs[T][16];      // x_t only (u in epilogue)
    __shared__ __align__(16) float Csh[2][24][25];

    const int tid = threadIdx.x;

    // ---- init staging (identical to R9) ----
    {
        const int i = tid >> 4, j = tid & 15;
        const float v = gA[tid];
        A_sh[i][j] = v; At_sh[j][i] = v;
        P_sh[0][i][j] = 0.0f;
        if (j < 4) P_sh[0][i][16 + j] = 0.0f;
    }
    if (tid < 128) {
        const int i = tid >> 3, j = tid & 7;
        const float v = gB[tid];
        B_sh[i][j] = v; Bt_sh[j][i] = v;
    }
    if (tid < 16) p_sh[0][tid] = 0.0f;
    for (int idx = tid; idx < T * NA; idx += 256) c_sh[idx / NA][idx % NA] = gc[idx];
    for (int idx = tid; idx < 576; idx += 256)
        Csh[0][idx / 24][idx % 24] = gC[(T - 1) * 576 + idx];
    __syncthreads();

    // ---- per-lane register caches of invariant rows ----
    float atr[16], btr_e[16], btr3[16], atr2[16], brow[8], browp[8];
    {
        const int rA  = tid >> 4;
        const int rBe = (tid >> 4) & 7;
        const int rB3 = (tid / 25) & 7;
        const int rA2 = (tid >> 3) & 15;
        const int rBp = tid & 15;
#pragma unroll
        for (int q = 0; q < 4; ++q) {
            float4 v;
            v = *(const float4*)&At_sh[rA][4 * q];
            atr[4*q]=v.x; atr[4*q+1]=v.y; atr[4*q+2]=v.z; atr[4*q+3]=v.w;
            v = *(const float4*)&Bt_sh[rBe][4 * q];
            btr_e[4*q]=v.x; btr_e[4*q+1]=v.y; btr_e[4*q+2]=v.z; btr_e[4*q+3]=v.w;
            v = *(const float4*)&Bt_sh[rB3][4 * q];
            btr3[4*q]=v.x; btr3[4*q+1]=v.y; btr3[4*q+2]=v.z; btr3[4*q+3]=v.w;
            v = *(const float4*)&At_sh[rA2][4 * q];
            atr2[4*q]=v.x; atr2[4*q+1]=v.y; atr2[4*q+2]=v.z; atr2[4*q+3]=v.w;
        }
#pragma unroll
        for (int q = 0; q < 2; ++q) {
            float4 v;
            v = *(const float4*)&B_sh[rA][4 * q];
            brow[4*q]=v.x; brow[4*q+1]=v.y; brow[4*q+2]=v.z; brow[4*q+3]=v.w;
            v = *(const float4*)&B_sh[rBp][4 * q];
            browp[4*q]=v.x; browp[4*q+1]=v.y; browp[4*q+2]=v.z; browp[4*q+3]=v.w;
        }
    }

    // ---- backward Riccati: 5 phases per step (byte-identical to R9) ----
    int pb = 0;
    for (int t = T - 1; t >= 0; --t) {
        const int cb = (T - 1 - t) & 1;

        float pf0 = 0.f, pf1 = 0.f, pf2 = 0.f;
        if (t > 0) {
            const float* src = gC + (size_t)(t - 1) * 576;
            pf0 = src[tid];
            pf1 = src[tid + 256];
            if (tid < 64) pf2 = src[tid + 512];
        }

        // phase 1: Wt = (P'A)^T, Vt = (P'B)^T
        {
            const int j = tid >> 4, k = tid & 15;
            Wt[j][k] = dot16r(&P_sh[pb][k][0], atr, 0.0f);
            if (tid < 128) {
                Vt[j][k] = dot16r(&P_sh[pb][k][0], btr_e, 0.0f);
            }
        }
        __syncthreads();

        // phase 2: Aug[0] = [H | G | rhs] and Gu = S + A^T P' B
        if (tid < 200) {
            const int i = tid / 25, j = tid % 25;
            float s;
            if (j < 8) {
                s = dot16r(&Vt[j][0], btr3, Csh[cb][16 + i][16 + j]);
            } else if (j < 24) {
                const int jj = j - 8;
                s = dot16r(&Wt[jj][0], btr3, Csh[cb][16 + i][jj]);
            } else {
                s = dot16r(&p_sh[pb][0], btr3, c_sh[t][16 + i]);
            }
            Aug[0][i][j] = s;
        }
        if (tid < 128) {
            const int i = tid >> 3, j = tid & 7;
            Gu[i][j] = dot16r(&Vt[j][0], atr2, Csh[cb][i][16 + j]);
        }
        __syncthreads();

        // phases 3+4: Gauss-Jordan, TWO rounds of 4x4 block pivots.
#pragma unroll
        for (int kk = 0; kk < 8; kk += 4) {
            const int rb = (kk >> 2) & 1, wb = rb ^ 1;
            const float m00=Aug[rb][kk+0][kk+0], m01=Aug[rb][kk+0][kk+1],
                        m02=Aug[rb][kk+0][kk+2], m03=Aug[rb][kk+0][kk+3];
            const float m10=Aug[rb][kk+1][kk+0], m11=Aug[rb][kk+1][kk+1],
                        m12=Aug[rb][kk+1][kk+2], m13=Aug[rb][kk+1][kk+3];
            const float m20=Aug[rb][kk+2][kk+0], m21=Aug[rb][kk+2][kk+1],
                        m22=Aug[rb][kk+2][kk+2], m23=Aug[rb][kk+2][kk+3];
            const float m30=Aug[rb][kk+3][kk+0], m31=Aug[rb][kk+3][kk+1],
                        m32=Aug[rb][kk+3][kk+2], m33=Aug[rb][kk+3][kk+3];
            const float ra   = 1.0f / fmaf(m00, m11, -m01 * m10);
            const float ai00 =  m11 * ra, ai01 = -m01 * ra;
            const float ai10 = -m10 * ra, ai11 =  m00 * ra;
            const float aib00 = ai00*m02 + ai01*m12, aib01 = ai00*m03 + ai01*m13;
            const float aib10 = ai10*m02 + ai11*m12, aib11 = ai10*m03 + ai11*m13;
            const float s00 = m22 - (m20*aib00 + m21*aib10);
            const float s01 = m23 - (m20*aib01 + m21*aib11);
            const float s10 = m32 - (m30*aib00 + m31*aib10);
            const float s11 = m33 - (m30*aib01 + m31*aib11);
            const float rs   = 1.0f / fmaf(s00, s11, -s01 * s10);
            const float si00 =  s11 * rs, si01 = -s01 * rs;
            const float si10 = -s10 * rs, si11 =  s00 * rs;
            if (tid < 200) {
                const int i = tid / 25, j = tid % 25;
                const float pt0 = Aug[rb][kk+0][j], pt1 = Aug[rb][kk+1][j];
                const float pq0 = Aug[rb][kk+2][j], pq1 = Aug[rb][kk+3][j];
                const float y0 = ai00*pt0 + ai01*pt1;
                const float y1 = ai10*pt0 + ai11*pt1;
                const float z0 = pq0 - (m20*y0 + m21*y1);
                const float z1 = pq1 - (m30*y0 + m31*y1);
                const float w2 = si00*z0 + si01*z1;
                const float w3 = si10*z0 + si11*z1;
                const float w0 = y0 - (aib00*w2 + aib01*w3);
                const float w1 = y1 - (aib10*w2 + aib11*w3);
                float v;
                if      (i == kk + 0) v = w0;
                else if (i == kk + 1) v = w1;
                else if (i == kk + 2) v = w2;
                else if (i == kk + 3) v = w3;
                else {
                    v = Aug[rb][i][j];
                    v = fmaf(-Aug[rb][i][kk+0], w0, v);
                    v = fmaf(-Aug[rb][i][kk+1], w1, v);
                    v = fmaf(-Aug[rb][i][kk+2], w2, v);
                    v = fmaf(-Aug[rb][i][kk+3], w3, v);
                }
                Aug[wb][i][j] = v;
                if (kk == 4 && j >= 8) {      // final round: export K,k
                    if (j < 24) Kall[t][i][j - 8] = v;
                    else        kall[t][i] = v;
                }
            }
            __syncthreads();
        }
        // Aug[0] = [I | K | k]

        // phase 5: P_t, p_t, F_t, d_t
        {
            const int i = tid >> 4, j = tid & 15;
            float kc[8];
#pragma unroll
            for (int y = 0; y < 8; ++y) kc[y] = Aug[0][y][8 + j];
            float s = dot16r(&Wt[j][0], atr, Csh[cb][i][j]);
            float s2 = 0.f;
            const float4 g0 = *(const float4*)&Gu[i][0];
            const float4 g1 = *(const float4*)&Gu[i][4];
            s2 = fmaf(g0.x, kc[0], s2); s2 = fmaf(g0.y, kc[1], s2);
            s2 = fmaf(g0.z, kc[2], s2); s2 = fmaf(g0.w, kc[3], s2);
            s2 = fmaf(g1.x, kc[4], s2); s2 = fmaf(g1.y, kc[5], s2);
            s2 = fmaf(g1.z, kc[6], s2); s2 = fmaf(g1.w, kc[7], s2);
            const float v = s - s2;
            P_sh[pb ^ 1][i][j] = v;
            Pws[t * 256 + tid] = v;
            float fa = 0.f;
#pragma unroll
            for (int y = 0; y < 8; ++y) fa = fmaf(brow[y], kc[y], fa);
            Fws[t * 256 + tid] = A_sh[i][j] - fa;
        }
        if (tid < 16) {
            float kk8[8];
#pragma unroll
            for (int q = 0; q < 8; ++q) kk8[q] = Aug[0][q][24];
            float s = dot16f4(&At_sh[tid][0], &p_sh[pb][0], c_sh[t][tid]);
            float s2 = 0.f;
#pragma unroll
            for (int q = 0; q < 8; ++q) s2 = fmaf(Gu[tid][q], kk8[q], s2);
            const float v = s - s2;
            p_sh[pb ^ 1][tid] = v;
            pws[t * 16 + tid] = v;
            float da = 0.f;
#pragma unroll
            for (int y = 0; y < 8; ++y) da = fmaf(browp[y], kk8[y], da);
            dws[t * 16 + tid] = -da;
        }
        if (t > 0) {
            Csh[cb ^ 1][tid / 24][tid % 24] = pf0;
            Csh[cb ^ 1][(tid + 256) / 24][(tid + 256) % 24] = pf1;
            if (tid < 64) Csh[cb ^ 1][(tid + 512) / 24][(tid + 512) % 24] = pf2;
        }
        __syncthreads();
        pb ^= 1;
    }
    // loop-end __syncthreads drained all ws stores (hipcc full-drain semantics)

    // ---- forward rollout: wave 0, in-register x-chain, ZERO barriers ----
    if (tid < 64) {
        const int l = tid;
        float x = 0.0f;
        float fcur[16] = {};
        float dcur = 0.0f;
        if (l < 16) {
            x = gx0[l];
            xs[0][l] = x;
#pragma unroll
            for (int q = 0; q < 4; ++q) {
                float4 v = *(const float4*)&Fws[l * 16 + 4 * q];
                fcur[4*q]=v.x; fcur[4*q+1]=v.y; fcur[4*q+2]=v.z; fcur[4*q+3]=v.w;
            }
            dcur = dws[l];
        }
        for (int t = 0; t < T - 1; ++t) {
            // prefetch F_{t+1}/d_{t+1} (consumed after the shfl step)
            float fn[16] = {};
            float dn = 0.0f;
            if (t < T - 2 && l < 16) {
#pragma unroll
                for (int q = 0; q < 4; ++q) {
                    float4 v = *(const float4*)&Fws[(t + 1) * 256 + l * 16 + 4 * q];
                    fn[4*q]=v.x; fn[4*q+1]=v.y; fn[4*q+2]=v.z; fn[4*q+3]=v.w;
                }
                dn = dws[(t + 1) * 16 + l];
            }
            // x_{t+1}[l] = d[l] + sum_q F[l][q] * x[q]  (broadcast via shfl)
            float s = dcur;
#pragma unroll
            for (int q = 0; q < 16; ++q) {
                const float xq = __shfl(x, q, 16);
                s = fmaf(fcur[q], xq, s);
            }
            x = s;
            if (l < 16) xs[t + 1][l] = x;
            if (t < T - 2 && l < 16) {
#pragma unroll
                for (int q = 0; q < 16; ++q) fcur[q] = fn[q];
                dcur = dn;
            }
        }
    }
    __syncthreads();

    // ---- epilogue: ONE parallel phase for u, mu, and z copy ----
    // u_t[y] = -(K_t[y] . x_t + k_t[y])  -> out[t*24 + 16 + y]
#pragma unroll
    for (int r = 0; r < 4; ++r) {
        const int u = tid + 256 * r;          // 0..1023
        const int t = u >> 3, y = u & 7;
        const float s = dot16f4(&Kall[t][y][0], &xs[t][0], kall[t][y]);
        out[t * 24 + 16 + y] = -s;
    }
    // x copy -> out[t*24 + i]
#pragma unroll
    for (int r = 0; r < 8; ++r) {
        const int o = tid + 256 * r;          // 0..2047
        const int t = o >> 4, i = o & 15;
        out[t * 24 + i] = xs[t][i];
    }
    // mu_t[i] = +/-(P_t[i] . x_t + p_t[i]) -> out[T*24 + t*16 + i]
#pragma unroll
    for (int r = 0; r < 8; ++r) {
        const int o = tid + 256 * r;          // 0..2047
        const int t = o >> 4, i = o & 15;
        float s = pws[t * 16 + i];
        const float4* Pr = (const float4*)(Pws + t * 256 + i * 16);
        const float4* zr = (const float4*)&xs[t][0];
#pragma unroll
        for (int q = 0; q < 4; ++q) {
            float4 p = Pr[q], z = zr[q];
            s = fmaf(p.x, z.x, s); s = fmaf(p.y, z.y, s);
            s = fmaf(p.z, z.z, s); s = fmaf(p.w, z.w, s);
        }
        if (t == 0) s = -s;                   // mu_0 = -(P_0 x_0 + p_0)
        out[T * 24 + o] = s;
    }
}

extern "C" void kernel_launch(void* const* d_in, const int* in_sizes, int n_in,
                              void* d_out, int out_size, void* d_ws, size_t ws_size,
                              hipStream_t stream) {
    const float* gA  = (const float*)d_in[0];
    const float* gB  = (const float*)d_in[1];
    const float* gx0 = (const float*)d_in[2];
    const float* gC  = (const float*)d_in[3];
    const float* gc  = (const float*)d_in[4];
    float* out = (float*)d_out;
    float* Pws = (float*)d_ws;           // T*256 floats
    float* pws = Pws + T * 256;          // T*16
    float* Fws = pws + T * 16;           // T*256
    float* dws = Fws + T * 256;          // T*16
    lqr_solve<<<dim3(1), dim3(256), 0, stream>>>(gA, gB, gx0, gC, gc, out,
                                                 Pws, pws, Fws, dws);
}

// Round 15
// 347.787 us; speedup vs baseline: 1.1606x; 1.0481x over previous
//
#include <hip/hip_runtime.h>

// LQR KKT solve via backward Riccati recursion + forward rollout.
// T=128, n_state=16, n_ctrl=8, n_all=24. Single block.
// Base: proven R9 (320us, absmax 0.002). SINGLE delta this round:
//   256 -> 512 threads (8 waves, 2/SIMD). Same algebra, same phases, same
//   barriers -- but tasks that R9 DOUBLED UP on one lane now run on
//   separate waves: phase1 Vt -> lanes 256-383; phase2 Gu -> lanes
//   256-383; phase5 p/d-task -> lanes 256-271. Each phase's per-lane
//   critical path becomes ONE task, and 2 waves/SIMD gives the scheduler
//   cross-wave latency overlap (R9 had 1 wave/SIMD = zero hiding).
// Ban list (measured): Gu dual-write (R3-R5), 1-wave layout (R8),
// sched_barrier (R10), asm light barriers (R11), per-lane 8x8 LU (R12),
// merged GJ round 2 (R10/R13), 1-step-prefetch shfl forward (R14).
// NOTE: C_t is TIME-VARYING -> P_t never converges; no freeze shortcuts.
// mu_t = P_t x_t + p_t (stable). d_ws: Pws|pws|Fws|dws.

constexpr int T  = 128;
constexpr int NA = 24;

// 16-elem dot: LDS float4 stream x register-resident row.
__device__ __forceinline__ float dot16r(const float* lds, const float* r, float s) {
    const float4* a4 = (const float4*)lds;
#pragma unroll
    for (int q = 0; q < 4; ++q) {
        float4 x = a4[q];
        s = fmaf(x.x, r[4 * q + 0], s); s = fmaf(x.y, r[4 * q + 1], s);
        s = fmaf(x.z, r[4 * q + 2], s); s = fmaf(x.w, r[4 * q + 3], s);
    }
    return s;
}
// 16-elem dot: both operands LDS float4.
__device__ __forceinline__ float dot16f4(const float* a, const float* b, float s) {
    const float4* a4 = (const float4*)a;
    const float4* b4 = (const float4*)b;
#pragma unroll
    for (int q = 0; q < 4; ++q) {
        float4 x = a4[q], y = b4[q];
        s = fmaf(x.x, y.x, s); s = fmaf(x.y, y.y, s);
        s = fmaf(x.z, y.z, s); s = fmaf(x.w, y.w, s);
    }
    return s;
}

__global__ __launch_bounds__(512, 1)
void lqr_solve(const float* __restrict__ gA,
               const float* __restrict__ gB,
               const float* __restrict__ gx0,
               const float* __restrict__ gC,
               const float* __restrict__ gc,
               float* __restrict__ out,
               float* __restrict__ Pws,   // [T*256] P_t row-major
               float* __restrict__ pws,   // [T*16]  p_t
               float* __restrict__ Fws,   // [T*256] F_t = A - B K_t
               float* __restrict__ dws)   // [T*16]  d_t = -B k_t
{
    __shared__ __align__(16) float A_sh[16][16];
    __shared__ __align__(16) float At_sh[16][16];
    __shared__ __align__(16) float B_sh[16][8];
    __shared__ __align__(16) float Bt_sh[8][16];
    __shared__ __align__(16) float P_sh[2][16][20];
    __shared__ __align__(16) float p_sh[2][16];
    __shared__ __align__(16) float Wt[16][20];
    __shared__ __align__(16) float Vt[8][20];
    __shared__ __align__(16) float Gu[16][8];
    __shared__ __align__(16) float Aug[2][8][28];
    __shared__ __align__(16) float Kall[T][8][16];
    __shared__ __align__(16) float kall[T][8];
    __shared__ __align__(16) float c_sh[T][NA];
    __shared__ __align__(16) float z_sh[T][NA];
    __shared__ __align__(16) float Csh[2][24][25];

    const int tid = threadIdx.x;

    // ---- init staging ----
    if (tid < 256) {
        const int i = tid >> 4, j = tid & 15;
        const float v = gA[tid];
        A_sh[i][j] = v; At_sh[j][i] = v;
        P_sh[0][i][j] = 0.0f;
        if (j < 4) P_sh[0][i][16 + j] = 0.0f;
    }
    if (tid < 128) {
        const int i = tid >> 3, j = tid & 7;
        const float v = gB[tid];
        B_sh[i][j] = v; Bt_sh[j][i] = v;
    }
    if (tid < 16) p_sh[0][tid] = 0.0f;
    for (int idx = tid; idx < T * NA; idx += 512) c_sh[idx / NA][idx % NA] = gc[idx];
    for (int idx = tid; idx < 576; idx += 512)
        Csh[0][idx / 24][idx % 24] = gC[(T - 1) * 576 + idx];
    __syncthreads();

    // ---- per-lane register caches of invariant rows ----
    // row formulas masked so every lane loads a valid index; only the
    // ranges noted actually use each cache.
    float atr[16], btr_e[16], btr3[16], atr2[16], brow[8], browp[8];
    {
        const int rA  = (tid >> 4) & 15;   // lanes<256: phase1 Wt + phase5 P/F
        const int rBe = (tid >> 4) & 7;    // lanes 256-383: phase1 Vt
        const int rB3 = (tid / 25) & 7;    // lanes<200: phase2 Aug
        const int rA2 = (tid >> 3) & 15;   // lanes 256-383: phase2 Gu
        const int rBp = tid & 15;          // lanes 256-271: phase5 d-task
#pragma unroll
        for (int q = 0; q < 4; ++q) {
            float4 v;
            v = *(const float4*)&At_sh[rA][4 * q];
            atr[4*q]=v.x; atr[4*q+1]=v.y; atr[4*q+2]=v.z; atr[4*q+3]=v.w;
            v = *(const float4*)&Bt_sh[rBe][4 * q];
            btr_e[4*q]=v.x; btr_e[4*q+1]=v.y; btr_e[4*q+2]=v.z; btr_e[4*q+3]=v.w;
            v = *(const float4*)&Bt_sh[rB3][4 * q];
            btr3[4*q]=v.x; btr3[4*q+1]=v.y; btr3[4*q+2]=v.z; btr3[4*q+3]=v.w;
            v = *(const float4*)&At_sh[rA2][4 * q];
            atr2[4*q]=v.x; atr2[4*q+1]=v.y; atr2[4*q+2]=v.z; atr2[4*q+3]=v.w;
        }
#pragma unroll
        for (int q = 0; q < 2; ++q) {
            float4 v;
            v = *(const float4*)&B_sh[rA][4 * q];
            brow[4*q]=v.x; brow[4*q+1]=v.y; brow[4*q+2]=v.z; brow[4*q+3]=v.w;
            v = *(const float4*)&B_sh[rBp][4 * q];
            browp[4*q]=v.x; browp[4*q+1]=v.y; browp[4*q+2]=v.z; browp[4*q+3]=v.w;
        }
    }

    // ---- backward Riccati: 5 phases per step (R9 structure) ----
    int pb = 0;
    for (int t = T - 1; t >= 0; --t) {
        const int cb = (T - 1 - t) & 1;

        // register-prefetch C_{t-1}: 576 words over 512 lanes (+64 extra)
        float pf0 = 0.f, pf1 = 0.f;
        if (t > 0) {
            const float* src = gC + (size_t)(t - 1) * 576;
            pf0 = src[tid];
            if (tid < 64) pf1 = src[512 + tid];
        }

        // phase 1: Wt (lanes<256) || Vt (lanes 256-383) -- de-duplicated
        if (tid < 256) {
            const int j = tid >> 4, k = tid & 15;
            Wt[j][k] = dot16r(&P_sh[pb][k][0], atr, 0.0f);
        } else if (tid < 384) {
            const int jb = (tid >> 4) & 7, k = tid & 15;
            Vt[jb][k] = dot16r(&P_sh[pb][k][0], btr_e, 0.0f);
        }
        __syncthreads();

        // phase 2: Aug (lanes<200) || Gu (lanes 256-383) -- de-duplicated
        if (tid < 200) {
            const int i = tid / 25, j = tid % 25;
            float s;
            if (j < 8) {
                s = dot16r(&Vt[j][0], btr3, Csh[cb][16 + i][16 + j]);
            } else if (j < 24) {
                const int jj = j - 8;
                s = dot16r(&Wt[jj][0], btr3, Csh[cb][16 + i][jj]);
            } else {
                s = dot16r(&p_sh[pb][0], btr3, c_sh[t][16 + i]);
            }
            Aug[0][i][j] = s;
        } else if (tid >= 256 && tid < 384) {
            const int i = (tid >> 3) & 15, j = tid & 7;
            Gu[i][j] = dot16r(&Vt[j][0], atr2, Csh[cb][i][16 + j]);
        }
        __syncthreads();

        // phases 3+4: Gauss-Jordan, TWO rounds of 4x4 block pivots (as R9)
#pragma unroll
        for (int kk = 0; kk < 8; kk += 4) {
            const int rb = (kk >> 2) & 1, wb = rb ^ 1;
            const float m00=Aug[rb][kk+0][kk+0], m01=Aug[rb][kk+0][kk+1],
                        m02=Aug[rb][kk+0][kk+2], m03=Aug[rb][kk+0][kk+3];
            const float m10=Aug[rb][kk+1][kk+0], m11=Aug[rb][kk+1][kk+1],
                        m12=Aug[rb][kk+1][kk+2], m13=Aug[rb][kk+1][kk+3];
            const float m20=Aug[rb][kk+2][kk+0], m21=Aug[rb][kk+2][kk+1],
                        m22=Aug[rb][kk+2][kk+2], m23=Aug[rb][kk+2][kk+3];
            const float m30=Aug[rb][kk+3][kk+0], m31=Aug[rb][kk+3][kk+1],
                        m32=Aug[rb][kk+3][kk+2], m33=Aug[rb][kk+3][kk+3];
            const float ra   = 1.0f / fmaf(m00, m11, -m01 * m10);
            const float ai00 =  m11 * ra, ai01 = -m01 * ra;
            const float ai10 = -m10 * ra, ai11 =  m00 * ra;
            const float aib00 = ai00*m02 + ai01*m12, aib01 = ai00*m03 + ai01*m13;
            const float aib10 = ai10*m02 + ai11*m12, aib11 = ai10*m03 + ai11*m13;
            const float s00 = m22 - (m20*aib00 + m21*aib10);
            const float s01 = m23 - (m20*aib01 + m21*aib11);
            const float s10 = m32 - (m30*aib00 + m31*aib10);
            const float s11 = m33 - (m30*aib01 + m31*aib11);
            const float rs   = 1.0f / fmaf(s00, s11, -s01 * s10);
            const float si00 =  s11 * rs, si01 = -s01 * rs;
            const float si10 = -s10 * rs, si11 =  s00 * rs;
            if (tid < 200) {
                const int i = tid / 25, j = tid % 25;
                const float pt0 = Aug[rb][kk+0][j], pt1 = Aug[rb][kk+1][j];
                const float pq0 = Aug[rb][kk+2][j], pq1 = Aug[rb][kk+3][j];
                const float y0 = ai00*pt0 + ai01*pt1;
                const float y1 = ai10*pt0 + ai11*pt1;
                const float z0 = pq0 - (m20*y0 + m21*y1);
                const float z1 = pq1 - (m30*y0 + m31*y1);
                const float w2 = si00*z0 + si01*z1;
                const float w3 = si10*z0 + si11*z1;
                const float w0 = y0 - (aib00*w2 + aib01*w3);
                const float w1 = y1 - (aib10*w2 + aib11*w3);
                float v;
                if      (i == kk + 0) v = w0;
                else if (i == kk + 1) v = w1;
                else if (i == kk + 2) v = w2;
                else if (i == kk + 3) v = w3;
                else {
                    v = Aug[rb][i][j];
                    v = fmaf(-Aug[rb][i][kk+0], w0, v);
                    v = fmaf(-Aug[rb][i][kk+1], w1, v);
                    v = fmaf(-Aug[rb][i][kk+2], w2, v);
                    v = fmaf(-Aug[rb][i][kk+3], w3, v);
                }
                Aug[wb][i][j] = v;
                if (kk == 4 && j >= 8) {      // final round: export K,k
                    if (j < 24) Kall[t][i][j - 8] = v;
                    else        kall[t][i] = v;
                }
            }
            __syncthreads();
        }
        // Aug[0] = [I | K | k]

        // phase 5: P/F (lanes<256) || p/d (lanes 256-271) -- de-duplicated
        if (tid < 256) {
            const int i = tid >> 4, j = tid & 15;
            float kc[8];
#pragma unroll
            for (int y = 0; y < 8; ++y) kc[y] = Aug[0][y][8 + j];
            float s = dot16r(&Wt[j][0], atr, Csh[cb][i][j]);
            float s2 = 0.f;
            const float4 g0 = *(const float4*)&Gu[i][0];
            const float4 g1 = *(const float4*)&Gu[i][4];
            s2 = fmaf(g0.x, kc[0], s2); s2 = fmaf(g0.y, kc[1], s2);
            s2 = fmaf(g0.z, kc[2], s2); s2 = fmaf(g0.w, kc[3], s2);
            s2 = fmaf(g1.x, kc[4], s2); s2 = fmaf(g1.y, kc[5], s2);
            s2 = fmaf(g1.z, kc[6], s2); s2 = fmaf(g1.w, kc[7], s2);
            const float v = s - s2;
            P_sh[pb ^ 1][i][j] = v;
            Pws[t * 256 + tid] = v;
            float fa = 0.f;
#pragma unroll
            for (int y = 0; y < 8; ++y) fa = fmaf(brow[y], kc[y], fa);
            Fws[t * 256 + tid] = A_sh[i][j] - fa;
        } else if (tid < 272) {
            const int l2 = tid - 256;
            float kk8[8];
#pragma unroll
            for (int q = 0; q < 8; ++q) kk8[q] = Aug[0][q][24];
            float s = dot16f4(&At_sh[l2][0], &p_sh[pb][0], c_sh[t][l2]);
            float s2 = 0.f;
#pragma unroll
            for (int q = 0; q < 8; ++q) s2 = fmaf(Gu[l2][q], kk8[q], s2);
            const float v = s - s2;
            p_sh[pb ^ 1][l2] = v;
            pws[t * 16 + l2] = v;
            float da = 0.f;
#pragma unroll
            for (int y = 0; y < 8; ++y) da = fmaf(browp[y], kk8[y], da);
            dws[t * 16 + l2] = -da;
        }
        if (t > 0) {  // commit prefetched C_{t-1}
            Csh[cb ^ 1][tid / 24][tid % 24] = pf0;
            if (tid < 64) {
                const int a = 512 + tid;
                Csh[cb ^ 1][a / 24][a % 24] = pf1;
            }
        }
        __syncthreads();
        pb ^= 1;
    }

    // ws stores complete before forward-pass reads
    __syncthreads();
    asm volatile("s_waitcnt vmcnt(0)" ::: "memory");

    // ---- forward rollout: one phase per step (identical to R9) ----
    if (tid < 16) z_sh[0][tid] = gx0[tid];
    float fcur[16], dcur = 0.f, prow[16], pcur = 0.f;
    if (tid < 16) {
#pragma unroll
        for (int q = 0; q < 4; ++q) {
            float4 v = *(const float4*)&Fws[tid * 16 + 4 * q];
            fcur[4*q]=v.x; fcur[4*q+1]=v.y; fcur[4*q+2]=v.z; fcur[4*q+3]=v.w;
        }
        dcur = dws[tid];
    }
    if (tid >= 32 && tid < 48) {
        const int i = tid - 32;
#pragma unroll
        for (int q = 0; q < 4; ++q) {
            float4 v = *(const float4*)&Pws[i * 16 + 4 * q];
            prow[4*q]=v.x; prow[4*q+1]=v.y; prow[4*q+2]=v.z; prow[4*q+3]=v.w;
        }
        pcur = pws[i];
    }
    __syncthreads();
    for (int t = 0; t < T; ++t) {
        float fn[16], dn = 0.f, pn[16], ppn = 0.f;
        if (t < T - 1) {
            if (tid < 16) {
#pragma unroll
                for (int q = 0; q < 4; ++q) {
                    float4 v = *(const float4*)&Fws[(t + 1) * 256 + tid * 16 + 4 * q];
                    fn[4*q]=v.x; fn[4*q+1]=v.y; fn[4*q+2]=v.z; fn[4*q+3]=v.w;
                }
                dn = dws[(t + 1) * 16 + tid];
            }
            if (tid >= 32 && tid < 48) {
                const int i = tid - 32;
#pragma unroll
                for (int q = 0; q < 4; ++q) {
                    float4 v = *(const float4*)&Pws[(t + 1) * 256 + i * 16 + 4 * q];
                    pn[4*q]=v.x; pn[4*q+1]=v.y; pn[4*q+2]=v.z; pn[4*q+3]=v.w;
                }
                ppn = pws[(t + 1) * 16 + i];
            }
        }
        if (tid >= 16 && tid < 24) {        // u_t = -(K_t x_t + k_t)
            const int y = tid - 16;
            float s = dot16f4(&Kall[t][y][0], &z_sh[t][0], kall[t][y]);
            z_sh[t][16 + y] = -s;
        }
        if (tid >= 32 && tid < 48) {        // mu_t = +/- (P_t x_t + p_t)
            const int i = tid - 32;
            float s = pcur;
            const float4* zr = (const float4*)&z_sh[t][0];
#pragma unroll
            for (int q = 0; q < 4; ++q) {
                float4 z = zr[q];
                s = fmaf(prow[4*q+0], z.x, s); s = fmaf(prow[4*q+1], z.y, s);
                s = fmaf(prow[4*q+2], z.z, s); s = fmaf(prow[4*q+3], z.w, s);
            }
            if (t == 0) s = -s;
            out[T * NA + t * 16 + i] = s;
        }
        if (t < T - 1 && tid < 16) {        // x_{t+1} = F_t x_t + d_t
            const float4* zr = (const float4*)&z_sh[t][0];
            float s = dcur;
#pragma unroll
            for (int q = 0; q < 4; ++q) {
                float4 z = zr[q];
                s = fmaf(fcur[4*q+0], z.x, s); s = fmaf(fcur[4*q+1], z.y, s);
                s = fmaf(fcur[4*q+2], z.z, s); s = fmaf(fcur[4*q+3], z.w, s);
            }
            z_sh[t + 1][tid] = s;
        }
        __syncthreads();
        if (t < T - 1) {
            if (tid < 16) {
#pragma unroll
                for (int q = 0; q < 16; ++q) fcur[q] = fn[q];
                dcur = dn;
            }
            if (tid >= 32 && tid < 48) {
#pragma unroll
                for (int q = 0; q < 16; ++q) prow[q] = pn[q];
                pcur = ppn;
            }
        }
    }

    // ---- write z ----
    for (int idx = tid; idx < T * NA; idx += 512)
        out[idx] = z_sh[idx / 24][idx % 24];
}

extern "C" void kernel_launch(void* const* d_in, const int* in_sizes, int n_in,
                              void* d_out, int out_size, void* d_ws, size_t ws_size,
                              hipStream_t stream) {
    const float* gA  = (const float*)d_in[0];
    const float* gB  = (const float*)d_in[1];
    const float* gx0 = (const float*)d_in[2];
    const float* gC  = (const float*)d_in[3];
    const float* gc  = (const float*)d_in[4];
    float* out = (float*)d_out;
    float* Pws = (float*)d_ws;           // T*256 floats
    float* pws = Pws + T * 256;          // T*16
    float* Fws = pws + T * 16;           // T*256
    float* dws = Fws + T * 256;          // T*16
    lqr_solve<<<dim3(1), dim3(512), 0, stream>>>(gA, gB, gx0, gC, gc, out,
                                                 Pws, pws, Fws, dws);
}